// Round 15
// baseline (223.539 us; speedup 1.0000x reference)
//
#include <hip/hip_runtime.h>
#include <hip/hip_bf16.h>

#define NN 8192
#define TOTD 128
#define HIDD 64
#define NHEAD 4
#define DHD 32
#define NCQ 16                // column splits for attention kernels
#define JPB (NN / 32 / NCQ)   // 16 column-tiles (jt) per block

typedef __attribute__((ext_vector_type(8))) short short8;
typedef __attribute__((ext_vector_type(4))) float f32x4;
typedef __attribute__((ext_vector_type(16))) float f32x16;

__device__ __forceinline__ short f2b(float f) {      // RTNE
  unsigned u = __builtin_bit_cast(unsigned, f);
  u += 0x7fff + ((u >> 16) & 1);
  return (short)(u >> 16);
}
__device__ __forceinline__ short f2b_fast(float f) { // round-half-up (P only, P>=0)
  unsigned u = __builtin_bit_cast(unsigned, f);
  return (short)((u + 0x8000u) >> 16);
}
__device__ __forceinline__ float b2f(short s) {
  unsigned u = ((unsigned)(unsigned short)s) << 16;
  return __builtin_bit_cast(float, u);
}
__device__ __forceinline__ float fexp2(float x) {
#if __has_builtin(__builtin_amdgcn_exp2f)
  return __builtin_amdgcn_exp2f(x);
#else
  return exp2f(x);
#endif
}
__device__ __forceinline__ f32x16 zero16() {
  f32x16 z;
#pragma unroll
  for (int i = 0; i < 16; ++i) z[i] = 0.f;
  return z;
}

// Fragment conventions (32x32x16, swapped QK = mfma(K, Q)):
//  A/B-frag: row/col = lane&31, k = (lane>>5)*8 + e
//  D: col = lane&31, row = (reg&3) + 8*(reg>>2) + 4*(lane>>5)
// X/V B-frags use permuted rows n(m,hi,e) = m*16 + (e&3) + 4*hi + 8*(e>>2),
// so P regs (pa0 = p[0..7], pa1 = p[8..15]) feed PV's A operand directly.
// Pf stores (pa0,pa1) per (rt, jt, lane): pv2 re-reads them as a pure GEMM.
//
// STABILITY NOTE (R8/R9/R13 post-mortems): pv1-family occupancy above ~21%
// (3+ blocks/CU) tips into an L2 dirty-line thrash regime (FETCH ~500 MB,
// WRITE amplified 1.5x, 4x slower). __launch_bounds__(256,2) on k_pv1 is
// load-bearing. R15: Pf/axq stores are non-temporal (streaming, no reuse
// before HBM round-trip) to remove dirty-line pressure on kb/xb.

// ---------------- K1: xb fragments (32x32 permuted rows) ---------------------
__global__ void k_build_xfrag(const float* __restrict__ in, const float* __restrict__ hx,
                              short* __restrict__ xb) {
  int i = blockIdx.x * 256 + threadIdx.x;   // over NN*TOTD, t-fastest
  int n = i >> 7;
  int t = i & 127;
  float v = (t < 64) ? in[n * 64 + t] : hx[n * 64 + (t - 64)];
  int jt = n >> 5, nn = n & 31;
  int m = nn >> 4, rem = nn & 15;
  int hi = (rem >> 2) & 1;
  int e = (rem & 3) | ((rem >> 3) << 2);
  int ct = t >> 5;
  int lane = (hi << 5) | (t & 31);
  xb[(((size_t)jt * 8 + ct * 2 + m) << 9) + (lane << 3) + e] = f2b(v);
}

// ---------------- K2: q,k projections (LDS-staged W, 16 rows/block) ----------
__global__ __launch_bounds__(256, 2) void k_qk(
    const float* __restrict__ in, const float* __restrict__ hx,
    const float* __restrict__ Wq, const float* __restrict__ Wk,
    short* __restrict__ qb, short* __restrict__ kb) {
  __shared__ float Ws[32 * 256];
  __shared__ float xr_t[128 * 16];   // [t][r]
  const int tid = threadIdx.x;
  const int n0 = blockIdx.x * 16;
  for (int i = tid; i < 2048; i += 256) {
    int r = i & 15, t = i >> 4;
    xr_t[t * 16 + r] = (t < 64) ? in[(n0 + r) * 64 + t] : hx[(n0 + r) * 64 + (t - 64)];
  }
  const int which = tid >> 7;
  const int h = (tid >> 5) & 3;
  const int d = tid & 31;
  const int c = tid;
  float acc[16];
#pragma unroll
  for (int r = 0; r < 16; ++r) acc[r] = 0.f;

  for (int pass = 0; pass < 4; ++pass) {
    __syncthreads();
    for (int i = tid; i < 32 * 256; i += 256) {
      int tt = pass * 32 + (i >> 8);
      int cc = i & 255;
      const float* W = (cc < 128) ? Wq : Wk;
      int hh = (cc >> 5) & 3, dd = cc & 31;
      Ws[(i >> 8) * 256 + cc] = W[((size_t)hh * 128 + tt) * 32 + dd];
    }
    __syncthreads();
#pragma unroll
    for (int t = 0; t < 32; ++t) {
      float wv = Ws[t * 256 + c];
      const float4* xp = (const float4*)&xr_t[(pass * 32 + t) * 16];
      float4 x0 = xp[0], x1 = xp[1], x2 = xp[2], x3 = xp[3];
      acc[0] += x0.x * wv;  acc[1] += x0.y * wv;  acc[2] += x0.z * wv;  acc[3] += x0.w * wv;
      acc[4] += x1.x * wv;  acc[5] += x1.y * wv;  acc[6] += x1.z * wv;  acc[7] += x1.w * wv;
      acc[8] += x2.x * wv;  acc[9] += x2.y * wv;  acc[10] += x2.z * wv; acc[11] += x2.w * wv;
      acc[12] += x3.x * wv; acc[13] += x3.y * wv; acc[14] += x3.z * wv; acc[15] += x3.w * wv;
    }
  }
#pragma unroll
  for (int r = 0; r < 16; ++r) {
    int n = n0 + r;
    int lane = (((d >> 3) & 1) << 5) | (n & 31);
    size_t idx = ((((size_t)(n >> 5) * 4 + h) * 2 + (d >> 4)) << 9) + (lane << 3) + (d & 7);
    if (which == 0) qb[idx] = f2b(acc[r] * 0.25503486f);   // log2(e)/sqrt(32)
    else            kb[idx] = f2b(acc[r]);
  }
}

// ---------------- K3a: partial softmax denominators (direct loads) -----------
__global__ __launch_bounds__(256, 4) void k_denom(
    const short* __restrict__ qb, const short* __restrict__ kb,
    float* __restrict__ lpart_g) {
  const int tid = threadIdx.x;
  const int w = tid >> 6, l = tid & 63;
  const int r0 = blockIdx.x * 128 + w * 32;
  const int rt = blockIdx.x * 4 + w;
  const int jt0 = blockIdx.y * JPB;

  short8 qf[NHEAD][2];
#pragma unroll
  for (int h = 0; h < NHEAD; ++h)
#pragma unroll
    for (int m = 0; m < 2; ++m)
      qf[h][m] = *(const short8*)&qb[((((size_t)rt * 4 + h) * 2 + m) << 9) + l * 8];

  float acc[NHEAD] = {0.f, 0.f, 0.f, 0.f};

  for (int j = 0; j < JPB; ++j) {
    const short* kbase = kb + (((size_t)(jt0 + j) * 8) << 9) + l * 8;
#pragma unroll
    for (int h = 0; h < NHEAD; ++h) {
      short8 kf0 = *(const short8*)&kbase[(h * 2 + 0) << 9];
      short8 kf1 = *(const short8*)&kbase[(h * 2 + 1) << 9];
      f32x16 s = __builtin_amdgcn_mfma_f32_32x32x16_bf16(kf0, qf[h][0], zero16(), 0, 0, 0);
      s = __builtin_amdgcn_mfma_f32_32x32x16_bf16(kf1, qf[h][1], s, 0, 0, 0);
#pragma unroll
      for (int r = 0; r < 16; ++r) acc[h] += fexp2(s[r]);
    }
  }
#pragma unroll
  for (int h = 0; h < NHEAD; ++h) acc[h] += __shfl_xor(acc[h], 32, 64);
  if (l < 32) {
#pragma unroll
    for (int h = 0; h < NHEAD; ++h)
      lpart_g[((size_t)blockIdx.y * NHEAD + h) * NN + r0 + l] = acc[h];
  }
}

// ---------------- K3b: linv = 0.25 / sum of NCQ partials ---------------------
__global__ void k_linv(const float* __restrict__ lpart_g, float* __restrict__ linv_g) {
  int i = blockIdx.x * 256 + threadIdx.x;      // over NHEAD*NN
  float s = 0.f;
#pragma unroll
  for (int q = 0; q < NCQ; ++q) s += lpart_g[(size_t)q * NHEAD * NN + i];
  linv_g[i] = 0.25f / s;
}

// ---------------- K3c: P in-register + ax partials + P store (nt) ------------
__global__ __launch_bounds__(256, 2) void k_pv1(
    const short* __restrict__ qb, const short* __restrict__ kb,
    const short* __restrict__ xb, const float* __restrict__ linv_g,
    short* __restrict__ axq, short* __restrict__ Pf, int storeP) {
  const int tid = threadIdx.x;
  const int w = tid >> 6, l = tid & 63;
  const int hi = l >> 5, col = l & 31;
  const int r0 = blockIdx.x * 128 + w * 32;
  const int rt = blockIdx.x * 4 + w;
  const int jt0 = blockIdx.y * JPB;

  short8 qf[NHEAD][2];
#pragma unroll
  for (int h = 0; h < NHEAD; ++h)
#pragma unroll
    for (int m = 0; m < 2; ++m)
      qf[h][m] = *(const short8*)&qb[((((size_t)rt * 4 + h) * 2 + m) << 9) + l * 8];
  float linv[NHEAD];
#pragma unroll
  for (int h = 0; h < NHEAD; ++h) linv[h] = linv_g[h * NN + r0 + col];

  f32x16 axa[4];
#pragma unroll
  for (int ct = 0; ct < 4; ++ct) axa[ct] = zero16();

  for (int j = 0; j < JPB; ++j) {
    const size_t jt = jt0 + j;
    const short* kbase = kb + ((jt * 8) << 9) + l * 8;
    const short* xbase = xb + ((jt * 8) << 9) + l * 8;
    short8 xv[8];
#pragma unroll
    for (int cchunk = 0; cchunk < 8; ++cchunk)
      xv[cchunk] = *(const short8*)&xbase[cchunk << 9];
    float p[16];
#pragma unroll
    for (int r = 0; r < 16; ++r) p[r] = 0.f;
#pragma unroll
    for (int h = 0; h < NHEAD; ++h) {
      short8 kf0 = *(const short8*)&kbase[(h * 2 + 0) << 9];
      short8 kf1 = *(const short8*)&kbase[(h * 2 + 1) << 9];
      f32x16 s = __builtin_amdgcn_mfma_f32_32x32x16_bf16(kf0, qf[h][0], zero16(), 0, 0, 0);
      s = __builtin_amdgcn_mfma_f32_32x32x16_bf16(kf1, qf[h][1], s, 0, 0, 0);
#pragma unroll
      for (int r = 0; r < 16; ++r) p[r] += fexp2(s[r]) * linv[h];
    }
    short8 pa0, pa1;
#pragma unroll
    for (int e = 0; e < 8; ++e) { pa0[e] = f2b_fast(p[e]); pa1[e] = f2b_fast(p[8 + e]); }
    if (storeP) {
      short8* pdst = (short8*)&Pf[(((size_t)rt * 256 + jt) << 10) + (l << 4)];
      __builtin_nontemporal_store(pa0, pdst + 0);
      __builtin_nontemporal_store(pa1, pdst + 1);
    }
#pragma unroll
    for (int ct = 0; ct < 4; ++ct) {
      axa[ct] = __builtin_amdgcn_mfma_f32_32x32x16_bf16(pa0, xv[ct * 2 + 0], axa[ct], 0, 0, 0);
      axa[ct] = __builtin_amdgcn_mfma_f32_32x32x16_bf16(pa1, xv[ct * 2 + 1], axa[ct], 0, 0, 0);
    }
  }
#pragma unroll
  for (int ct = 0; ct < 4; ++ct)
#pragma unroll
    for (int r = 0; r < 16; ++r) {
      int row = (r & 3) + 8 * (r >> 2) + 4 * hi;
      __builtin_nontemporal_store(
          f2b(axa[ct][r]),
          &axq[(size_t)blockIdx.y * NN * TOTD + (size_t)(r0 + row) * TOTD + ct * 32 + col]);
    }
}

// ---------------- K4: ax reduce + r,z gates (8 rows/block) -------------------
__global__ __launch_bounds__(256) void k_rz(
    const short* __restrict__ axq, const float* __restrict__ hx,
    const float* __restrict__ Wr, const float* __restrict__ br,
    const float* __restrict__ Wz, const float* __restrict__ bz,
    float* __restrict__ ax, float* __restrict__ z, short* __restrict__ v2f) {
  __shared__ float axs[8][TOTD];
  const int tid = threadIdx.x;
  const int n0 = blockIdx.x * 8;
  for (int i = tid; i < 8 * TOTD; i += 256) {
    int rw = i >> 7, c = i & 127;
    int n = n0 + rw;
    float s = 0.f;
#pragma unroll
    for (int q = 0; q < NCQ; ++q) s += b2f(axq[((size_t)q * NN + n) * TOTD + c]);
    axs[rw][c] = s;
    if (c < 64) ax[(size_t)n * HIDD + c] = s;   // only ax[:, :64] is consumed later
  }
  __syncthreads();
  const int c2 = tid & 127;
  const int half = tid >> 7;
  const bool isz = c2 >= HIDD;
  const int c = c2 & (HIDD - 1);
  const float* W = isz ? Wz : Wr;
  const float bias = isz ? bz[c] : br[c];
  float a0 = bias, a1 = bias, a2 = bias, a3 = bias;
#pragma unroll
  for (int t = 0; t < TOTD; ++t) {
    float wv = W[t * HIDD + c];
    a0 += axs[half * 4 + 0][t] * wv;
    a1 += axs[half * 4 + 1][t] * wv;
    a2 += axs[half * 4 + 2][t] * wv;
    a3 += axs[half * 4 + 3][t] * wv;
  }
  float accs[4] = {a0, a1, a2, a3};
#pragma unroll
  for (int r = 0; r < 4; ++r) {
    int n = n0 + half * 4 + r;
    float sg = 1.f / (1.f + __expf(-accs[r]));
    if (isz) {
      z[(size_t)n * HIDD + c] = sg;
    } else {
      int jt = n >> 5, nn = n & 31;
      int m = nn >> 4, rem = nn & 15;
      int hh = (rem >> 2) & 1;
      int e = (rem & 3) | ((rem >> 3) << 2);
      int ct = c >> 5;
      int lane = (hh << 5) | (c & 31);
      v2f[(((size_t)jt * 4 + ct * 2 + m) << 9) + (lane << 3) + e] = f2b(sg * hx[(size_t)n * HIDD + c]);
    }
  }
}

// ---------------- K5a: a2 partials from stored P (pure GEMM) -----------------
__global__ __launch_bounds__(256, 4) void k_pv2P(
    const short* __restrict__ Pf, const short* __restrict__ v2f,
    short* __restrict__ a2q) {
  const int tid = threadIdx.x;
  const int w = tid >> 6, l = tid & 63;
  const int hi = l >> 5, col = l & 31;
  const int r0 = blockIdx.x * 128 + w * 32;
  const int rt = blockIdx.x * 4 + w;
  const int jt0 = blockIdx.y * JPB;

  f32x16 a2a[2];
#pragma unroll
  for (int ct = 0; ct < 2; ++ct) a2a[ct] = zero16();

  for (int j = 0; j < JPB; ++j) {
    const size_t jt = jt0 + j;
    const short8* pbase = (const short8*)&Pf[(((size_t)rt * 256 + jt) << 10) + (l << 4)];
    short8 pa0 = pbase[0];
    short8 pa1 = pbase[1];
    const short* vbase = v2f + ((jt * 4) << 9) + l * 8;
    short8 vv0 = *(const short8*)&vbase[0 << 9];
    short8 vv1 = *(const short8*)&vbase[1 << 9];
    short8 vv2 = *(const short8*)&vbase[2 << 9];
    short8 vv3 = *(const short8*)&vbase[3 << 9];
    a2a[0] = __builtin_amdgcn_mfma_f32_32x32x16_bf16(pa0, vv0, a2a[0], 0, 0, 0);
    a2a[0] = __builtin_amdgcn_mfma_f32_32x32x16_bf16(pa1, vv1, a2a[0], 0, 0, 0);
    a2a[1] = __builtin_amdgcn_mfma_f32_32x32x16_bf16(pa0, vv2, a2a[1], 0, 0, 0);
    a2a[1] = __builtin_amdgcn_mfma_f32_32x32x16_bf16(pa1, vv3, a2a[1], 0, 0, 0);
  }
#pragma unroll
  for (int ct = 0; ct < 2; ++ct)
#pragma unroll
    for (int r = 0; r < 16; ++r) {
      int row = (r & 3) + 8 * (r >> 2) + 4 * hi;
      a2q[(size_t)blockIdx.y * NN * HIDD + (size_t)(r0 + row) * HIDD + ct * 32 + col] =
          f2b(a2a[ct][r]);
    }
}

// ---------------- K5b: a2 partials recomputing P (fallback) ------------------
__global__ __launch_bounds__(256, 3) void k_pv2R(
    const short* __restrict__ qb, const short* __restrict__ kb,
    const short* __restrict__ v2f, const float* __restrict__ linv_g,
    short* __restrict__ a2q) {
  const int tid = threadIdx.x;
  const int w = tid >> 6, l = tid & 63;
  const int hi = l >> 5, col = l & 31;
  const int r0 = blockIdx.x * 128 + w * 32;
  const int rt = blockIdx.x * 4 + w;
  const int jt0 = blockIdx.y * JPB;

  short8 qf[NHEAD][2];
#pragma unroll
  for (int h = 0; h < NHEAD; ++h)
#pragma unroll
    for (int m = 0; m < 2; ++m)
      qf[h][m] = *(const short8*)&qb[((((size_t)rt * 4 + h) * 2 + m) << 9) + l * 8];
  float linv[NHEAD];
#pragma unroll
  for (int h = 0; h < NHEAD; ++h) linv[h] = linv_g[h * NN + r0 + col];

  f32x16 a2a[2];
#pragma unroll
  for (int ct = 0; ct < 2; ++ct) a2a[ct] = zero16();

  for (int j = 0; j < JPB; ++j) {
    const size_t jt = jt0 + j;
    const short* kbase = kb + ((jt * 8) << 9) + l * 8;
    const short* vbase = v2f + ((jt * 4) << 9) + l * 8;
    short8 vv0 = *(const short8*)&vbase[0 << 9];
    short8 vv1 = *(const short8*)&vbase[1 << 9];
    short8 vv2 = *(const short8*)&vbase[2 << 9];
    short8 vv3 = *(const short8*)&vbase[3 << 9];
    float p[16];
#pragma unroll
    for (int r = 0; r < 16; ++r) p[r] = 0.f;
#pragma unroll
    for (int h = 0; h < NHEAD; ++h) {
      short8 kf0 = *(const short8*)&kbase[(h * 2 + 0) << 9];
      short8 kf1 = *(const short8*)&kbase[(h * 2 + 1) << 9];
      f32x16 s = __builtin_amdgcn_mfma_f32_32x32x16_bf16(kf0, qf[h][0], zero16(), 0, 0, 0);
      s = __builtin_amdgcn_mfma_f32_32x32x16_bf16(kf1, qf[h][1], s, 0, 0, 0);
#pragma unroll
      for (int r = 0; r < 16; ++r) p[r] += fexp2(s[r]) * linv[h];
    }
    short8 pa0, pa1;
#pragma unroll
    for (int e = 0; e < 8; ++e) { pa0[e] = f2b_fast(p[e]); pa1[e] = f2b_fast(p[8 + e]); }
    a2a[0] = __builtin_amdgcn_mfma_f32_32x32x16_bf16(pa0, vv0, a2a[0], 0, 0, 0);
    a2a[0] = __builtin_amdgcn_mfma_f32_32x32x16_bf16(pa1, vv1, a2a[0], 0, 0, 0);
    a2a[1] = __builtin_amdgcn_mfma_f32_32x32x16_bf16(pa0, vv2, a2a[1], 0, 0, 0);
    a2a[1] = __builtin_amdgcn_mfma_f32_32x32x16_bf16(pa1, vv3, a2a[1], 0, 0, 0);
  }
#pragma unroll
  for (int ct = 0; ct < 2; ++ct)
#pragma unroll
    for (int r = 0; r < 16; ++r) {
      int row = (r & 3) + 8 * (r >> 2) + 4 * hi;
      a2q[(size_t)blockIdx.y * NN * HIDD + (size_t)(r0 + row) * HIDD + ct * 32 + col] =
          f2b(a2a[ct][r]);
    }
}

// ---------------- K6: a2 reduce + GRU epilogue -------------------------------
__global__ __launch_bounds__(256) void k_final(
    const short* __restrict__ a2q, const float* __restrict__ ax,
    const float* __restrict__ hx, const float* __restrict__ Wh,
    const float* __restrict__ bh, const float* __restrict__ z,
    float* __restrict__ out) {
  __shared__ float Whs[TOTD * HIDD];
  __shared__ float a2s[16][HIDD];
  const int tid = threadIdx.x;
  const int r0 = blockIdx.x * 16;

  for (int i = tid; i < TOTD * HIDD; i += 256) Whs[i] = Wh[i];
  for (int i = tid; i < 16 * HIDD; i += 256) {
    int rw = i >> 6, c = i & 63;
    size_t gi = (size_t)(r0 + rw) * HIDD + c;
    float s = 0.f;
#pragma unroll
    for (int q = 0; q < NCQ; ++q) s += b2f(a2q[(size_t)q * NN * HIDD + gi]);
    a2s[rw][c] = s;
  }
  __syncthreads();
  for (int o = tid; o < 16 * HIDD; o += 256) {
    int rw = o >> 6, c = o & 63;
    const float* axrow = &ax[(size_t)(r0 + rw) * HIDD];   // ax holds only 64 cols
    float acc = bh[c];
#pragma unroll
    for (int t = 0; t < 64; ++t) acc += axrow[t] * Whs[t * HIDD + c];
#pragma unroll
    for (int t = 0; t < 64; ++t) acc += a2s[rw][t] * Whs[(64 + t) * HIDD + c];
    float hval = tanhf(acc);
    size_t gi = (size_t)(r0 + rw) * HIDD + c;
    float zz = z[gi];
    out[gi] = zz * hx[gi] + (1.f - zz) * hval;
  }
}

extern "C" void kernel_launch(void* const* d_in, const int* in_sizes, int n_in,
                              void* d_out, int out_size, void* d_ws, size_t ws_size,
                              hipStream_t stream) {
  const float* in = (const float*)d_in[0];
  const float* hx = (const float*)d_in[1];
  const float* Wq = (const float*)d_in[2];
  const float* Wk = (const float*)d_in[3];
  const float* Wr = (const float*)d_in[4];
  const float* br = (const float*)d_in[5];
  const float* Wz = (const float*)d_in[6];
  const float* bz = (const float*)d_in[7];
  const float* Wh = (const float*)d_in[8];
  const float* bh = (const float*)d_in[9];

  const size_t MB = 1ull << 20;
  char* ws = (char*)d_ws;
  short* qb    = (short*)(ws + 0 * MB);              // 2 MB
  short* kb    = (short*)(ws + 2 * MB);              // 2 MB
  short* xb    = (short*)(ws + 4 * MB);              // 2 MB
  float* linv  = (float*)(ws + 6 * MB);              // 128 KB
  float* lpart = (float*)(ws + 6 * MB + 524288);     // 512 KB
  float* ax    = (float*)(ws + 7 * MB);              // 2 MB (64 cols, f32)
  float* z     = (float*)(ws + 9 * MB);              // 2 MB
  short* v2f   = (short*)(ws + 11 * MB);             // 1 MB
  short* axq   = (short*)(ws + 12 * MB);             // 32 MB (NCQ slices, bf16)
  short* a2q   = (short*)(ws + 44 * MB);             // 16 MB (NCQ slices, bf16)
  short* Pf    = (short*)(ws + 60 * MB);             // 128 MB (optional)
  float* out   = (float*)d_out;
  int useP = (ws_size >= 188 * MB) ? 1 : 0;

  k_build_xfrag<<<dim3((NN * TOTD) / 256), dim3(256), 0, stream>>>(in, hx, xb);
  k_qk<<<dim3(NN / 16), dim3(256), 0, stream>>>(in, hx, Wq, Wk, qb, kb);
  k_denom<<<dim3(NN / 128, NCQ), dim3(256), 0, stream>>>(qb, kb, lpart);
  k_linv<<<dim3((NHEAD * NN) / 256), dim3(256), 0, stream>>>(lpart, linv);
  k_pv1<<<dim3(NN / 128, NCQ), dim3(256), 0, stream>>>(qb, kb, xb, linv, axq, Pf, useP);
  k_rz<<<dim3(NN / 8), dim3(256), 0, stream>>>(axq, hx, Wr, br, Wz, bz, ax, z, v2f);
  if (useP)
    k_pv2P<<<dim3(NN / 128, NCQ), dim3(256), 0, stream>>>(Pf, v2f, a2q);
  else
    k_pv2R<<<dim3(NN / 128, NCQ), dim3(256), 0, stream>>>(qb, kb, v2f, linv, a2q);
  k_final<<<dim3(NN / 16), dim3(256), 0, stream>>>(a2q, ax, hx, Wh, bh, z, out);
}

// Round 16
// 200.994 us; speedup vs baseline: 1.1122x; 1.1122x over previous
//
#include <hip/hip_runtime.h>
#include <hip/hip_bf16.h>

#define NN 8192
#define TOTD 128
#define HIDD 64
#define NHEAD 4
#define DHD 32
#define NCQ 16                 // column splits for denom / pv2
#define JPB (NN / 32 / NCQ)    // 16 column-tiles per block (denom/pv2)
#define NCQ1 8                 // column splits for pv1 (halved: fewer partials)
#define JPB1 (NN / 32 / NCQ1)  // 32 column-tiles per block (pv1)

typedef __attribute__((ext_vector_type(8))) short short8;
typedef __attribute__((ext_vector_type(4))) float f32x4;
typedef __attribute__((ext_vector_type(16))) float f32x16;

__device__ __forceinline__ short f2b(float f) {      // RTNE
  unsigned u = __builtin_bit_cast(unsigned, f);
  u += 0x7fff + ((u >> 16) & 1);
  return (short)(u >> 16);
}
__device__ __forceinline__ short f2b_fast(float f) { // round-half-up (P only, P>=0)
  unsigned u = __builtin_bit_cast(unsigned, f);
  return (short)((u + 0x8000u) >> 16);
}
__device__ __forceinline__ float b2f(short s) {
  unsigned u = ((unsigned)(unsigned short)s) << 16;
  return __builtin_bit_cast(float, u);
}
__device__ __forceinline__ float fexp2(float x) {
#if __has_builtin(__builtin_amdgcn_exp2f)
  return __builtin_amdgcn_exp2f(x);
#else
  return exp2f(x);
#endif
}
__device__ __forceinline__ f32x16 zero16() {
  f32x16 z;
#pragma unroll
  for (int i = 0; i < 16; ++i) z[i] = 0.f;
  return z;
}

// Fragment conventions (32x32x16, swapped QK = mfma(K, Q)):
//  A/B-frag: row/col = lane&31, k = (lane>>5)*8 + e
//  D: col = lane&31, row = (reg&3) + 8*(reg>>2) + 4*(lane>>5)
// X/V B-frags use permuted rows n(m,hi,e) = m*16 + (e&3) + 4*hi + 8*(e>>2),
// so P regs (pa0 = p[0..7], pa1 = p[8..15]) feed PV's A operand directly.
// Pf stores (pa0,pa1) per (rt, jt, lane): pv2 re-reads them as a pure GEMM.
//
// STABILITY NOTE (R8/R9/R13/R15 post-mortems): pv1-family occupancy above
// ~21% (3+ blocks/CU) tips into an L2 thrash regime (FETCH ~500 MB, 4x
// slower). __launch_bounds__(256,2) on k_pv1 is load-bearing. Non-temporal
// stores on axq/Pf hurt downstream consumers (R15). NCQ1=8 keeps pv1 at the
// same 2 blocks/CU while halving axq partial-reduce traffic in k_rz.

// ---------------- K1: xb fragments (32x32 permuted rows) ---------------------
__global__ void k_build_xfrag(const float* __restrict__ in, const float* __restrict__ hx,
                              short* __restrict__ xb) {
  int i = blockIdx.x * 256 + threadIdx.x;   // over NN*TOTD, t-fastest
  int n = i >> 7;
  int t = i & 127;
  float v = (t < 64) ? in[n * 64 + t] : hx[n * 64 + (t - 64)];
  int jt = n >> 5, nn = n & 31;
  int m = nn >> 4, rem = nn & 15;
  int hi = (rem >> 2) & 1;
  int e = (rem & 3) | ((rem >> 3) << 2);
  int ct = t >> 5;
  int lane = (hi << 5) | (t & 31);
  xb[(((size_t)jt * 8 + ct * 2 + m) << 9) + (lane << 3) + e] = f2b(v);
}

// ---------------- K2: q,k projections (LDS-staged W, 16 rows/block) ----------
__global__ __launch_bounds__(256, 2) void k_qk(
    const float* __restrict__ in, const float* __restrict__ hx,
    const float* __restrict__ Wq, const float* __restrict__ Wk,
    short* __restrict__ qb, short* __restrict__ kb) {
  __shared__ float Ws[32 * 256];
  __shared__ float xr_t[128 * 16];   // [t][r]
  const int tid = threadIdx.x;
  const int n0 = blockIdx.x * 16;
  for (int i = tid; i < 2048; i += 256) {
    int r = i & 15, t = i >> 4;
    xr_t[t * 16 + r] = (t < 64) ? in[(n0 + r) * 64 + t] : hx[(n0 + r) * 64 + (t - 64)];
  }
  const int which = tid >> 7;
  const int h = (tid >> 5) & 3;
  const int d = tid & 31;
  const int c = tid;
  float acc[16];
#pragma unroll
  for (int r = 0; r < 16; ++r) acc[r] = 0.f;

  for (int pass = 0; pass < 4; ++pass) {
    __syncthreads();
    for (int i = tid; i < 32 * 256; i += 256) {
      int tt = pass * 32 + (i >> 8);
      int cc = i & 255;
      const float* W = (cc < 128) ? Wq : Wk;
      int hh = (cc >> 5) & 3, dd = cc & 31;
      Ws[(i >> 8) * 256 + cc] = W[((size_t)hh * 128 + tt) * 32 + dd];
    }
    __syncthreads();
#pragma unroll
    for (int t = 0; t < 32; ++t) {
      float wv = Ws[t * 256 + c];
      const float4* xp = (const float4*)&xr_t[(pass * 32 + t) * 16];
      float4 x0 = xp[0], x1 = xp[1], x2 = xp[2], x3 = xp[3];
      acc[0] += x0.x * wv;  acc[1] += x0.y * wv;  acc[2] += x0.z * wv;  acc[3] += x0.w * wv;
      acc[4] += x1.x * wv;  acc[5] += x1.y * wv;  acc[6] += x1.z * wv;  acc[7] += x1.w * wv;
      acc[8] += x2.x * wv;  acc[9] += x2.y * wv;  acc[10] += x2.z * wv; acc[11] += x2.w * wv;
      acc[12] += x3.x * wv; acc[13] += x3.y * wv; acc[14] += x3.z * wv; acc[15] += x3.w * wv;
    }
  }
#pragma unroll
  for (int r = 0; r < 16; ++r) {
    int n = n0 + r;
    int lane = (((d >> 3) & 1) << 5) | (n & 31);
    size_t idx = ((((size_t)(n >> 5) * 4 + h) * 2 + (d >> 4)) << 9) + (lane << 3) + (d & 7);
    if (which == 0) qb[idx] = f2b(acc[r] * 0.25503486f);   // log2(e)/sqrt(32)
    else            kb[idx] = f2b(acc[r]);
  }
}

// ---------------- K3a: partial softmax denominators (direct loads) -----------
__global__ __launch_bounds__(256, 4) void k_denom(
    const short* __restrict__ qb, const short* __restrict__ kb,
    float* __restrict__ lpart_g) {
  const int tid = threadIdx.x;
  const int w = tid >> 6, l = tid & 63;
  const int r0 = blockIdx.x * 128 + w * 32;
  const int rt = blockIdx.x * 4 + w;
  const int jt0 = blockIdx.y * JPB;

  short8 qf[NHEAD][2];
#pragma unroll
  for (int h = 0; h < NHEAD; ++h)
#pragma unroll
    for (int m = 0; m < 2; ++m)
      qf[h][m] = *(const short8*)&qb[((((size_t)rt * 4 + h) * 2 + m) << 9) + l * 8];

  float acc[NHEAD] = {0.f, 0.f, 0.f, 0.f};

  for (int j = 0; j < JPB; ++j) {
    const short* kbase = kb + (((size_t)(jt0 + j) * 8) << 9) + l * 8;
#pragma unroll
    for (int h = 0; h < NHEAD; ++h) {
      short8 kf0 = *(const short8*)&kbase[(h * 2 + 0) << 9];
      short8 kf1 = *(const short8*)&kbase[(h * 2 + 1) << 9];
      f32x16 s = __builtin_amdgcn_mfma_f32_32x32x16_bf16(kf0, qf[h][0], zero16(), 0, 0, 0);
      s = __builtin_amdgcn_mfma_f32_32x32x16_bf16(kf1, qf[h][1], s, 0, 0, 0);
#pragma unroll
      for (int r = 0; r < 16; ++r) acc[h] += fexp2(s[r]);
    }
  }
#pragma unroll
  for (int h = 0; h < NHEAD; ++h) acc[h] += __shfl_xor(acc[h], 32, 64);
  if (l < 32) {
#pragma unroll
    for (int h = 0; h < NHEAD; ++h)
      lpart_g[((size_t)blockIdx.y * NHEAD + h) * NN + r0 + l] = acc[h];
  }
}

// ---------------- K3b: linv = 0.25 / sum of NCQ partials ---------------------
__global__ void k_linv(const float* __restrict__ lpart_g, float* __restrict__ linv_g) {
  int i = blockIdx.x * 256 + threadIdx.x;      // over NHEAD*NN
  float s = 0.f;
#pragma unroll
  for (int q = 0; q < NCQ; ++q) s += lpart_g[(size_t)q * NHEAD * NN + i];
  linv_g[i] = 0.25f / s;
}

// ---------------- K3c: P in-register + ax partials + P store -----------------
__global__ __launch_bounds__(256, 2) void k_pv1(
    const short* __restrict__ qb, const short* __restrict__ kb,
    const short* __restrict__ xb, const float* __restrict__ linv_g,
    short* __restrict__ axq, short* __restrict__ Pf, int storeP) {
  const int tid = threadIdx.x;
  const int w = tid >> 6, l = tid & 63;
  const int hi = l >> 5, col = l & 31;
  const int r0 = blockIdx.x * 128 + w * 32;
  const int rt = blockIdx.x * 4 + w;
  const int jt0 = blockIdx.y * JPB1;

  short8 qf[NHEAD][2];
#pragma unroll
  for (int h = 0; h < NHEAD; ++h)
#pragma unroll
    for (int m = 0; m < 2; ++m)
      qf[h][m] = *(const short8*)&qb[((((size_t)rt * 4 + h) * 2 + m) << 9) + l * 8];
  float linv[NHEAD];
#pragma unroll
  for (int h = 0; h < NHEAD; ++h) linv[h] = linv_g[h * NN + r0 + col];

  f32x16 axa[4];
#pragma unroll
  for (int ct = 0; ct < 4; ++ct) axa[ct] = zero16();

  for (int j = 0; j < JPB1; ++j) {
    const size_t jt = jt0 + j;
    const short* kbase = kb + ((jt * 8) << 9) + l * 8;
    const short* xbase = xb + ((jt * 8) << 9) + l * 8;
    short8 xv[8];
#pragma unroll
    for (int cchunk = 0; cchunk < 8; ++cchunk)
      xv[cchunk] = *(const short8*)&xbase[cchunk << 9];
    float p[16];
#pragma unroll
    for (int r = 0; r < 16; ++r) p[r] = 0.f;
#pragma unroll
    for (int h = 0; h < NHEAD; ++h) {
      short8 kf0 = *(const short8*)&kbase[(h * 2 + 0) << 9];
      short8 kf1 = *(const short8*)&kbase[(h * 2 + 1) << 9];
      f32x16 s = __builtin_amdgcn_mfma_f32_32x32x16_bf16(kf0, qf[h][0], zero16(), 0, 0, 0);
      s = __builtin_amdgcn_mfma_f32_32x32x16_bf16(kf1, qf[h][1], s, 0, 0, 0);
#pragma unroll
      for (int r = 0; r < 16; ++r) p[r] += fexp2(s[r]) * linv[h];
    }
    short8 pa0, pa1;
#pragma unroll
    for (int e = 0; e < 8; ++e) { pa0[e] = f2b_fast(p[e]); pa1[e] = f2b_fast(p[8 + e]); }
    if (storeP) {
      short8* pdst = (short8*)&Pf[(((size_t)rt * 256 + jt) << 10) + (l << 4)];
      pdst[0] = pa0;
      pdst[1] = pa1;
    }
#pragma unroll
    for (int ct = 0; ct < 4; ++ct) {
      axa[ct] = __builtin_amdgcn_mfma_f32_32x32x16_bf16(pa0, xv[ct * 2 + 0], axa[ct], 0, 0, 0);
      axa[ct] = __builtin_amdgcn_mfma_f32_32x32x16_bf16(pa1, xv[ct * 2 + 1], axa[ct], 0, 0, 0);
    }
  }
#pragma unroll
  for (int ct = 0; ct < 4; ++ct)
#pragma unroll
    for (int r = 0; r < 16; ++r) {
      int row = (r & 3) + 8 * (r >> 2) + 4 * hi;
      axq[(size_t)blockIdx.y * NN * TOTD + (size_t)(r0 + row) * TOTD + ct * 32 + col] =
          f2b(axa[ct][r]);
    }
}

// ---------------- K4: ax reduce + r,z gates (8 rows/block) -------------------
__global__ __launch_bounds__(256) void k_rz(
    const short* __restrict__ axq, const float* __restrict__ hx,
    const float* __restrict__ Wr, const float* __restrict__ br,
    const float* __restrict__ Wz, const float* __restrict__ bz,
    float* __restrict__ ax, float* __restrict__ z, short* __restrict__ v2f) {
  __shared__ float axs[8][TOTD];
  const int tid = threadIdx.x;
  const int n0 = blockIdx.x * 8;
  for (int i = tid; i < 8 * TOTD; i += 256) {
    int rw = i >> 7, c = i & 127;
    int n = n0 + rw;
    float s = 0.f;
#pragma unroll
    for (int q = 0; q < NCQ1; ++q) s += b2f(axq[((size_t)q * NN + n) * TOTD + c]);
    axs[rw][c] = s;
    if (c < 64) ax[(size_t)n * HIDD + c] = s;   // only ax[:, :64] is consumed later
  }
  __syncthreads();
  const int c2 = tid & 127;
  const int half = tid >> 7;
  const bool isz = c2 >= HIDD;
  const int c = c2 & (HIDD - 1);
  const float* W = isz ? Wz : Wr;
  const float bias = isz ? bz[c] : br[c];
  float a0 = bias, a1 = bias, a2 = bias, a3 = bias;
#pragma unroll
  for (int t = 0; t < TOTD; ++t) {
    float wv = W[t * HIDD + c];
    a0 += axs[half * 4 + 0][t] * wv;
    a1 += axs[half * 4 + 1][t] * wv;
    a2 += axs[half * 4 + 2][t] * wv;
    a3 += axs[half * 4 + 3][t] * wv;
  }
  float accs[4] = {a0, a1, a2, a3};
#pragma unroll
  for (int r = 0; r < 4; ++r) {
    int n = n0 + half * 4 + r;
    float sg = 1.f / (1.f + __expf(-accs[r]));
    if (isz) {
      z[(size_t)n * HIDD + c] = sg;
    } else {
      int jt = n >> 5, nn = n & 31;
      int m = nn >> 4, rem = nn & 15;
      int hh = (rem >> 2) & 1;
      int e = (rem & 3) | ((rem >> 3) << 2);
      int ct = c >> 5;
      int lane = (hh << 5) | (c & 31);
      v2f[(((size_t)jt * 4 + ct * 2 + m) << 9) + (lane << 3) + e] = f2b(sg * hx[(size_t)n * HIDD + c]);
    }
  }
}

// ---------------- K5a: a2 partials from stored P (pure GEMM) -----------------
__global__ __launch_bounds__(256, 4) void k_pv2P(
    const short* __restrict__ Pf, const short* __restrict__ v2f,
    short* __restrict__ a2q) {
  const int tid = threadIdx.x;
  const int w = tid >> 6, l = tid & 63;
  const int hi = l >> 5, col = l & 31;
  const int r0 = blockIdx.x * 128 + w * 32;
  const int rt = blockIdx.x * 4 + w;
  const int jt0 = blockIdx.y * JPB;

  f32x16 a2a[2];
#pragma unroll
  for (int ct = 0; ct < 2; ++ct) a2a[ct] = zero16();

  for (int j = 0; j < JPB; ++j) {
    const size_t jt = jt0 + j;
    const short8* pbase = (const short8*)&Pf[(((size_t)rt * 256 + jt) << 10) + (l << 4)];
    short8 pa0 = pbase[0];
    short8 pa1 = pbase[1];
    const short* vbase = v2f + ((jt * 4) << 9) + l * 8;
    short8 vv0 = *(const short8*)&vbase[0 << 9];
    short8 vv1 = *(const short8*)&vbase[1 << 9];
    short8 vv2 = *(const short8*)&vbase[2 << 9];
    short8 vv3 = *(const short8*)&vbase[3 << 9];
    a2a[0] = __builtin_amdgcn_mfma_f32_32x32x16_bf16(pa0, vv0, a2a[0], 0, 0, 0);
    a2a[0] = __builtin_amdgcn_mfma_f32_32x32x16_bf16(pa1, vv1, a2a[0], 0, 0, 0);
    a2a[1] = __builtin_amdgcn_mfma_f32_32x32x16_bf16(pa0, vv2, a2a[1], 0, 0, 0);
    a2a[1] = __builtin_amdgcn_mfma_f32_32x32x16_bf16(pa1, vv3, a2a[1], 0, 0, 0);
  }
#pragma unroll
  for (int ct = 0; ct < 2; ++ct)
#pragma unroll
    for (int r = 0; r < 16; ++r) {
      int row = (r & 3) + 8 * (r >> 2) + 4 * hi;
      a2q[(size_t)blockIdx.y * NN * HIDD + (size_t)(r0 + row) * HIDD + ct * 32 + col] =
          f2b(a2a[ct][r]);
    }
}

// ---------------- K5b: a2 partials recomputing P (fallback) ------------------
__global__ __launch_bounds__(256, 3) void k_pv2R(
    const short* __restrict__ qb, const short* __restrict__ kb,
    const short* __restrict__ v2f, const float* __restrict__ linv_g,
    short* __restrict__ a2q) {
  const int tid = threadIdx.x;
  const int w = tid >> 6, l = tid & 63;
  const int hi = l >> 5, col = l & 31;
  const int r0 = blockIdx.x * 128 + w * 32;
  const int rt = blockIdx.x * 4 + w;
  const int jt0 = blockIdx.y * JPB;

  short8 qf[NHEAD][2];
#pragma unroll
  for (int h = 0; h < NHEAD; ++h)
#pragma unroll
    for (int m = 0; m < 2; ++m)
      qf[h][m] = *(const short8*)&qb[((((size_t)rt * 4 + h) * 2 + m) << 9) + l * 8];
  float linv[NHEAD];
#pragma unroll
  for (int h = 0; h < NHEAD; ++h) linv[h] = linv_g[h * NN + r0 + col];

  f32x16 a2a[2];
#pragma unroll
  for (int ct = 0; ct < 2; ++ct) a2a[ct] = zero16();

  for (int j = 0; j < JPB; ++j) {
    const size_t jt = jt0 + j;
    const short* kbase = kb + ((jt * 8) << 9) + l * 8;
    const short* vbase = v2f + ((jt * 4) << 9) + l * 8;
    short8 vv0 = *(const short8*)&vbase[0 << 9];
    short8 vv1 = *(const short8*)&vbase[1 << 9];
    short8 vv2 = *(const short8*)&vbase[2 << 9];
    short8 vv3 = *(const short8*)&vbase[3 << 9];
    float p[16];
#pragma unroll
    for (int r = 0; r < 16; ++r) p[r] = 0.f;
#pragma unroll
    for (int h = 0; h < NHEAD; ++h) {
      short8 kf0 = *(const short8*)&kbase[(h * 2 + 0) << 9];
      short8 kf1 = *(const short8*)&kbase[(h * 2 + 1) << 9];
      f32x16 s = __builtin_amdgcn_mfma_f32_32x32x16_bf16(kf0, qf[h][0], zero16(), 0, 0, 0);
      s = __builtin_amdgcn_mfma_f32_32x32x16_bf16(kf1, qf[h][1], s, 0, 0, 0);
#pragma unroll
      for (int r = 0; r < 16; ++r) p[r] += fexp2(s[r]) * linv[h];
    }
    short8 pa0, pa1;
#pragma unroll
    for (int e = 0; e < 8; ++e) { pa0[e] = f2b_fast(p[e]); pa1[e] = f2b_fast(p[8 + e]); }
    a2a[0] = __builtin_amdgcn_mfma_f32_32x32x16_bf16(pa0, vv0, a2a[0], 0, 0, 0);
    a2a[0] = __builtin_amdgcn_mfma_f32_32x32x16_bf16(pa1, vv1, a2a[0], 0, 0, 0);
    a2a[1] = __builtin_amdgcn_mfma_f32_32x32x16_bf16(pa0, vv2, a2a[1], 0, 0, 0);
    a2a[1] = __builtin_amdgcn_mfma_f32_32x32x16_bf16(pa1, vv3, a2a[1], 0, 0, 0);
  }
#pragma unroll
  for (int ct = 0; ct < 2; ++ct)
#pragma unroll
    for (int r = 0; r < 16; ++r) {
      int row = (r & 3) + 8 * (r >> 2) + 4 * hi;
      a2q[(size_t)blockIdx.y * NN * HIDD + (size_t)(r0 + row) * HIDD + ct * 32 + col] =
          f2b(a2a[ct][r]);
    }
}

// ---------------- K6: a2 reduce + GRU epilogue -------------------------------
__global__ __launch_bounds__(256) void k_final(
    const short* __restrict__ a2q, const float* __restrict__ ax,
    const float* __restrict__ hx, const float* __restrict__ Wh,
    const float* __restrict__ bh, const float* __restrict__ z,
    float* __restrict__ out) {
  __shared__ float Whs[TOTD * HIDD];
  __shared__ float a2s[16][HIDD];
  const int tid = threadIdx.x;
  const int r0 = blockIdx.x * 16;

  for (int i = tid; i < TOTD * HIDD; i += 256) Whs[i] = Wh[i];
  for (int i = tid; i < 16 * HIDD; i += 256) {
    int rw = i >> 6, c = i & 63;
    size_t gi = (size_t)(r0 + rw) * HIDD + c;
    float s = 0.f;
#pragma unroll
    for (int q = 0; q < NCQ; ++q) s += b2f(a2q[(size_t)q * NN * HIDD + gi]);
    a2s[rw][c] = s;
  }
  __syncthreads();
  for (int o = tid; o < 16 * HIDD; o += 256) {
    int rw = o >> 6, c = o & 63;
    const float* axrow = &ax[(size_t)(r0 + rw) * HIDD];   // ax holds only 64 cols
    float acc = bh[c];
#pragma unroll
    for (int t = 0; t < 64; ++t) acc += axrow[t] * Whs[t * HIDD + c];
#pragma unroll
    for (int t = 0; t < 64; ++t) acc += a2s[rw][t] * Whs[(64 + t) * HIDD + c];
    float hval = tanhf(acc);
    size_t gi = (size_t)(r0 + rw) * HIDD + c;
    float zz = z[gi];
    out[gi] = zz * hx[gi] + (1.f - zz) * hval;
  }
}

extern "C" void kernel_launch(void* const* d_in, const int* in_sizes, int n_in,
                              void* d_out, int out_size, void* d_ws, size_t ws_size,
                              hipStream_t stream) {
  const float* in = (const float*)d_in[0];
  const float* hx = (const float*)d_in[1];
  const float* Wq = (const float*)d_in[2];
  const float* Wk = (const float*)d_in[3];
  const float* Wr = (const float*)d_in[4];
  const float* br = (const float*)d_in[5];
  const float* Wz = (const float*)d_in[6];
  const float* bz = (const float*)d_in[7];
  const float* Wh = (const float*)d_in[8];
  const float* bh = (const float*)d_in[9];

  const size_t MB = 1ull << 20;
  char* ws = (char*)d_ws;
  short* qb    = (short*)(ws + 0 * MB);              // 2 MB
  short* kb    = (short*)(ws + 2 * MB);              // 2 MB
  short* xb    = (short*)(ws + 4 * MB);              // 2 MB
  float* linv  = (float*)(ws + 6 * MB);              // 128 KB
  float* lpart = (float*)(ws + 6 * MB + 524288);     // 512 KB
  float* ax    = (float*)(ws + 7 * MB);              // 2 MB (64 cols, f32)
  float* z     = (float*)(ws + 9 * MB);              // 2 MB
  short* v2f   = (short*)(ws + 11 * MB);             // 1 MB
  short* axq   = (short*)(ws + 12 * MB);             // 16 MB (NCQ1 slices, bf16)
  short* a2q   = (short*)(ws + 44 * MB);             // 16 MB (NCQ slices, bf16)
  short* Pf    = (short*)(ws + 60 * MB);             // 128 MB (optional)
  float* out   = (float*)d_out;
  int useP = (ws_size >= 188 * MB) ? 1 : 0;

  k_build_xfrag<<<dim3((NN * TOTD) / 256), dim3(256), 0, stream>>>(in, hx, xb);
  k_qk<<<dim3(NN / 16), dim3(256), 0, stream>>>(in, hx, Wq, Wk, qb, kb);
  k_denom<<<dim3(NN / 128, NCQ), dim3(256), 0, stream>>>(qb, kb, lpart);
  k_linv<<<dim3((NHEAD * NN) / 256), dim3(256), 0, stream>>>(lpart, linv);
  k_pv1<<<dim3(NN / 128, NCQ1), dim3(256), 0, stream>>>(qb, kb, xb, linv, axq, Pf, useP);
  k_rz<<<dim3(NN / 8), dim3(256), 0, stream>>>(axq, hx, Wr, br, Wz, bz, ax, z, v2f);
  if (useP)
    k_pv2P<<<dim3(NN / 128, NCQ), dim3(256), 0, stream>>>(Pf, v2f, a2q);
  else
    k_pv2R<<<dim3(NN / 128, NCQ), dim3(256), 0, stream>>>(qb, kb, v2f, linv, a2q);
  k_final<<<dim3(NN / 16), dim3(256), 0, stream>>>(a2q, ax, hx, Wh, bh, z, out);
}